// Round 5
// baseline (349.136 us; speedup 1.0000x reference)
//
#include <hip/hip_runtime.h>
#include <stdint.h>

typedef __attribute__((ext_vector_type(8))) short s16x8;   // 8 bf16 (4 VGPRs)
typedef __attribute__((ext_vector_type(4))) float f32x4;   // 4 fp32 acc

__device__ __forceinline__ unsigned short f2bf(float f){
  union { float f; unsigned u; } v; v.f = f;
  return (unsigned short)((v.u + 0x7FFFu + ((v.u>>16)&1u))>>16);
}
__device__ __forceinline__ float bf2f(unsigned short u){
  union { unsigned u; float f; } c; c.u = ((unsigned)u)<<16; return c.f;
}
#if __has_builtin(__builtin_amdgcn_cvt_pk_bf16_f32)
__device__ __forceinline__ unsigned pkbf(float a, float b){
  typedef __attribute__((ext_vector_type(2))) __bf16 bf16x2;
  union { bf16x2 v; unsigned u; } c;
  c.v = __builtin_amdgcn_cvt_pk_bf16_f32(a, b);
  return c.u;
}
#else
__device__ __forceinline__ unsigned pkbf(float a, float b){
  return (unsigned)f2bf(a) | ((unsigned)f2bf(b)<<16);
}
#endif

// async global->LDS, 16B/lane; LDS dest = wave-uniform base + lane*16.
// Global address is PER-LANE -> we can gather any permutation into lane-linear LDS.
__device__ __forceinline__ void g2l16(const void* g, void* l){
  auto* lp = reinterpret_cast<__attribute__((address_space(3))) unsigned int*>(
      reinterpret_cast<uintptr_t>(l));
  auto* gp = reinterpret_cast<const __attribute__((address_space(1))) unsigned int*>(
      reinterpret_cast<uintptr_t>(g));
  __builtin_amdgcn_global_load_lds(gp, lp, 16, 0, 0);
}

// =====================================================================
// Prep: q/k/v fp32 -> bf16. grid (2048,1,3) x 256, 8 elems/thread.
// (mask stays fp32 — read directly in attn; unique 64 MB lives in L3)
// =====================================================================
__global__ __launch_bounds__(256) void cvt_qkv(
    const float* __restrict__ q, const float* __restrict__ k, const float* __restrict__ v,
    unsigned short* __restrict__ qo, unsigned short* __restrict__ ko, unsigned short* __restrict__ vo)
{
  const int z = blockIdx.z;
  const float* src = (z==0)?q:(z==1)?k:v;
  unsigned short* dst = (z==0)?qo:(z==1)?ko:vo;
  const int i8 = (blockIdx.x*256 + threadIdx.x)*8;
  const float4 a = *(const float4*)&src[i8];
  const float4 b = *(const float4*)&src[i8+4];
  uint4 o;
  o.x = pkbf(a.x,a.y); o.y = pkbf(a.z,a.w);
  o.z = pkbf(b.x,b.y); o.w = pkbf(b.z,b.w);
  *(uint4*)&dst[i8] = o;
}

// =====================================================================
// Weight transpose+convert: Wt[n][k] = bf16(W[k][n]).  grid (8,8,4).
// =====================================================================
__global__ __launch_bounds__(256) void convert_wT(
    const float* __restrict__ W0, const float* __restrict__ W1,
    const float* __restrict__ W2, const float* __restrict__ W3,
    unsigned short* __restrict__ T0, unsigned short* __restrict__ T1,
    unsigned short* __restrict__ T2, unsigned short* __restrict__ T3)
{
  __shared__ float Ts[64][65];
  const int z = blockIdx.z;
  const float* W = (z==0)?W0:(z==1)?W1:(z==2)?W2:W3;
  unsigned short* Wt = (z==0)?T0:(z==1)?T1:(z==2)?T2:T3;
  const int t = threadIdx.x;
  const int k0 = blockIdx.x*64, n0 = blockIdx.y*64;
  {
    const int r = t>>4, c = (t&15)*4;
#pragma unroll
    for (int rr=0; rr<4; ++rr){
      const float4 w4 = *(const float4*)&W[(size_t)(k0 + r + rr*16)*512 + n0 + c];
      Ts[r+rr*16][c]   = w4.x; Ts[r+rr*16][c+1] = w4.y;
      Ts[r+rr*16][c+2] = w4.z; Ts[r+rr*16][c+3] = w4.w;
    }
  }
  __syncthreads();
  const int n = t>>2, kc = (t&3)*16;
  unsigned o[8];
#pragma unroll
  for (int i=0;i<16;i+=2) o[i>>1] = pkbf(Ts[kc+i][n], Ts[kc+i+1][n]);
  *(uint4*)&Wt[(size_t)(n0+n)*512 + k0 + kc]     = *(uint4*)&o[0];
  *(uint4*)&Wt[(size_t)(n0+n)*512 + k0 + kc + 8] = *(uint4*)&o[4];
}

// =====================================================================
// m97-style GEMM: 128x128 tile, BK=64, bf16 A/B, global_load_lds staging
// with global-side XOR chunk swizzle.
// EPI 0 (z=0,1,2): qkv -> Qp/Kp [B,H,S,64] (Q scaled 1/8), Vtg [B,H,64,S]
// EPI 1: out-proj -> bf16 [8192][512]
// =====================================================================
template<int EPI>
__global__ __launch_bounds__(256) void gemm_m97(
    const unsigned short* __restrict__ A0, const unsigned short* __restrict__ A1,
    const unsigned short* __restrict__ A2,
    const unsigned short* __restrict__ W0, const unsigned short* __restrict__ W1,
    const unsigned short* __restrict__ W2,
    const float* __restrict__ b0, const float* __restrict__ b1, const float* __restrict__ b2,
    unsigned short* __restrict__ Oq, unsigned short* __restrict__ Ok,
    unsigned short* __restrict__ Ov, unsigned short* __restrict__ Oflat)
{
  __shared__ unsigned short As[128*64];
  __shared__ unsigned short Bs[128*64];
  const int t = threadIdx.x;
  const int lane = t & 63;
  const int w = t >> 6;
  const int l16 = lane & 15;
  const int quad = lane >> 4;
  const int wm = w & 1, wn = w >> 1;
  const int bm = blockIdx.x, bn = blockIdx.y;
  const int z = (EPI==0) ? (int)blockIdx.z : 0;
  const unsigned short* A  = (z==0)?A0:(z==1)?A1:A2;
  const unsigned short* Wt = (z==0)?W0:(z==1)?W1:W2;
  const float* bias        = (z==0)?b0:(z==1)?b1:b2;

  const int Lr = lane >> 3;          // 0..7 row within 8-row group
  const int gc = (lane & 7) ^ Lr;    // global chunk (XOR swizzle)

  f32x4 acc[4][4];
#pragma unroll
  for(int i=0;i<4;i++)
#pragma unroll
    for(int j=0;j<4;j++) acc[i][j] = (f32x4){0.f,0.f,0.f,0.f};

  for (int kt=0; kt<8; ++kt){
    const int k0 = kt*64;
#pragma unroll
    for (int j=0;j<4;++j){
      const int rb = w*32 + j*8;
      g2l16(&A [(size_t)(bm*128 + rb + Lr)*512 + k0 + gc*8], &As[rb*64]);
      g2l16(&Wt[(size_t)(bn*128 + rb + Lr)*512 + k0 + gc*8], &Bs[rb*64]);
    }
    __syncthreads();
#pragma unroll
    for (int kk=0;kk<2;++kk){
      s16x8 af[4], bfr[4];
#pragma unroll
      for (int mt=0;mt<4;++mt){
        const int row = wm*64 + mt*16 + l16;
        af[mt] = *(const s16x8*)&As[row*64 + (((kk*4+quad) ^ (row&7))*8)];
      }
#pragma unroll
      for (int nt=0;nt<4;++nt){
        const int row = wn*64 + nt*16 + l16;
        bfr[nt] = *(const s16x8*)&Bs[row*64 + (((kk*4+quad) ^ (row&7))*8)];
      }
#pragma unroll
      for (int mt=0;mt<4;++mt)
#pragma unroll
        for (int nt=0;nt<4;++nt)
          acc[mt][nt] = __builtin_amdgcn_mfma_f32_16x16x32_bf16(af[mt], bfr[nt], acc[mt][nt], 0,0,0);
    }
    __syncthreads();
  }

#pragma unroll
  for (int mt=0;mt<4;++mt){
    const int gm = bm*128 + wm*64 + mt*16 + quad*4;
    const int b_ = gm>>11, s = gm & 2047;
#pragma unroll
    for (int nt=0;nt<4;++nt){
      const int gn = bn*128 + wn*64 + nt*16 + l16;
      const float bv = bias[gn];
      if (EPI==1){
#pragma unroll
        for (int r=0;r<4;++r)
          Oflat[(size_t)(gm+r)*512 + gn] = f2bf(acc[mt][nt][r] + bv);
      } else if (z==2){
        const int hh = gn>>6, dk = gn&63;
        uint2 uu;
        uu.x = pkbf(acc[mt][nt][0]+bv, acc[mt][nt][1]+bv);
        uu.y = pkbf(acc[mt][nt][2]+bv, acc[mt][nt][3]+bv);
        *(uint2*)&Ov[(((size_t)b_*8 + hh)*64 + dk)*2048 + s] = uu;
      } else {
        const int hh = gn>>6, dk = gn&63;
        unsigned short* Out = (z==0)?Oq:Ok;
        const float scl = (z==0)?0.125f:1.0f;
#pragma unroll
        for (int r=0;r<4;++r)
          Out[(((size_t)b_*8 + hh)*2048 + (s+r))*64 + dk] = f2bf((acc[mt][nt][r]+bv)*scl);
      }
    }
  }
}

// =====================================================================
// Attention v4: S^T = K Q^T; 32 q/wave; frag-major K staging (zero-VALU,
// conflict-free lane-linear LDS reads); group-padded V; PV via the
// PROVEN shuffle-regroup + 16x16x32 path (O^T = V^T P^T).
// grid (8,16,4) x 256 (4 waves x 32 q = 128 q).
// =====================================================================
__global__ __launch_bounds__(256,2) void attn_kernel(
    const unsigned short* __restrict__ Qp, const unsigned short* __restrict__ Kp,
    const unsigned short* __restrict__ Vt, const float* __restrict__ mask,
    unsigned short* __restrict__ Ap)
{
  // K: 8 frags x 1024B, lane-linear (frag f = nt*2+kk)
  // V: 8 groups x (8 rows x 128B + 32B pad) = 1056B -> phase-shifted banks
  __shared__ unsigned short Ks[2][8*512];
  __shared__ unsigned short Vs[2][8*528];
  const int t = threadIdx.x;
  const int lane = t & 63;
  const int w = t >> 6;              // 0..3
  const int l16 = lane & 15;
  const int quad = lane >> 4;
  const int h = blockIdx.x, qt = blockIdx.y, b = blockIdx.z;
  const int q0 = qt*128 + w*32;      // per-wave q base
  const unsigned short* Qb = Qp + ((size_t)b*8 + h)*2048*64;
  const unsigned short* Kb = Kp + ((size_t)b*8 + h)*2048*64;
  const unsigned short* Vb = Vt + ((size_t)b*8 + h)*64*2048;
  const float* mb = mask + (size_t)b*2048*2048;

  // Q fragments (pre-scaled 1/8): B-operand of 16x16x32, n=q, k=d
  s16x8 qf[2][2];
#pragma unroll
  for (int tc=0;tc<2;++tc)
#pragma unroll
    for (int kk=0;kk<2;++kk)
      qf[tc][kk] = *(const s16x8*)&Qb[(size_t)(q0 + tc*16 + l16)*64 + kk*32 + quad*8];

  // staging gather offsets (elements)
  int koffs[2], voffs[2];
#pragma unroll
  for (int j=0;j<2;++j){
    // K frag f=2w+j: nt=w, kk=j; lane L holds (row=nt*16+(L&15), chunk=kk*4+(L>>4))
    koffs[j] = ((w*16 + (lane&15))*64) + ((j*4 + (lane>>4))*8);
    // V group g=2w+j: row 8g+(L>>3), chunk (L&7)^(L>>3)
    voffs[j] = (((2*w+j)*8 + (lane>>3))*2048) + (((lane&7) ^ (lane>>3))*8);
  }
  // prologue: stage tile 0
#pragma unroll
  for (int j=0;j<2;++j){
    g2l16(Kb + koffs[j], &Ks[0][(2*w+j)*512]);
    g2l16(Vb + voffs[j], &Vs[0][(2*w+j)*528]);
  }

  f32x4 o_acc[2][4];
#pragma unroll
  for(int tc=0;tc<2;++tc)
#pragma unroll
    for(int nt=0;nt<4;++nt) o_acc[tc][nt]=(f32x4){0.f,0.f,0.f,0.f};
  float l_run[2] = {0.f, 0.f};

  const int b3 = l16>>3, a7 = l16&7;
  const float* mrow0 = mb + (size_t)(q0 + l16)*2048 + quad*4;
  const float* mrow1 = mrow0 + (size_t)16*2048;

  union U8 { unsigned u[4]; s16x8 v; };

  for (int kt=0; kt<32; ++kt){
    const int cur = kt&1;
    const int kbase = kt*64;
    __syncthreads();   // buf[cur] staged; prior reads of buf[cur^1] done

    // mask loads FIRST (so waiting on them leaves the prefetch in flight)
    float4 mr[2][4];
#pragma unroll
    for (int nt=0;nt<4;++nt){
      mr[0][nt] = *(const float4*)&mrow0[kbase + nt*16];
      mr[1][nt] = *(const float4*)&mrow1[kbase + nt*16];
    }
    // prefetch next tile into buf[cur^1]
    if (kt<31){
      const int kb2 = (kt+1)*64;
#pragma unroll
      for (int j=0;j<2;++j){
        g2l16(Kb + (size_t)kb2*64 + koffs[j], &Ks[cur^1][(2*w+j)*512]);
        g2l16(Vb + kb2 + voffs[j],            &Vs[cur^1][(2*w+j)*528]);
      }
    }

    // S^T = K Q^T : sc[tc][nt] -> q=l16(col), k=nt*16+quad*4+r(row)
    f32x4 sc[2][4];
#pragma unroll
    for(int tc=0;tc<2;++tc)
#pragma unroll
      for(int nt=0;nt<4;++nt) sc[tc][nt]=(f32x4){0.f,0.f,0.f,0.f};
#pragma unroll
    for (int nt=0;nt<4;++nt)
#pragma unroll
      for (int kk=0;kk<2;++kk){
        const s16x8 kf = *(const s16x8*)&Ks[cur][(nt*2+kk)*512 + lane*8];
#pragma unroll
        for (int tc=0;tc<2;++tc)
          sc[tc][nt] = __builtin_amdgcn_mfma_f32_16x16x32_bf16(kf, qf[tc][kk], sc[tc][nt],0,0,0);
      }

    // softmax + shuffle-regroup into B-frag of 16x16x32 (PROVEN r2/r3 path)
#pragma unroll
    for (int tc=0;tc<2;++tc){
      unsigned pk[8];
      float rs = 0.f;
#pragma unroll
      for (int nt=0;nt<4;++nt){
        float x0 = sc[tc][nt][0]*mr[tc][nt].x, x1 = sc[tc][nt][1]*mr[tc][nt].y;
        float x2 = sc[tc][nt][2]*mr[tc][nt].z, x3 = sc[tc][nt][3]*mr[tc][nt].w;
        x0 = (x0>0.f)?x0:-10000.f; x1 = (x1>0.f)?x1:-10000.f;
        x2 = (x2>0.f)?x2:-10000.f; x3 = (x3>0.f)?x3:-10000.f;
        const float e0 = __expf(x0), e1 = __expf(x1), e2 = __expf(x2), e3 = __expf(x3);
        rs += (e0+e1)+(e2+e3);
        pk[nt*2]   = pkbf(e0, e1);
        pk[nt*2+1] = pkbf(e2, e3);
      }
      rs += __shfl_xor(rs, 16);
      rs += __shfl_xor(rs, 32);
      l_run[tc] += rs;
      U8 pu[2];
#pragma unroll
      for (int kk=0;kk<2;++kk)
#pragma unroll
        for (int c=0;c<4;++c){
          const int srcLane = (((quad&1)*2 + (c>>1))<<4) | l16;
          const int vA = __shfl((int)pk[kk*4 + (c&1)],     srcLane);
          const int vB = __shfl((int)pk[kk*4 + 2 + (c&1)], srcLane);
          pu[kk].u[c] = (quad < 2) ? (unsigned)vA : (unsigned)vB;
        }
      // O^T += V^T P^T  (A-operand = V^T from group-padded LDS)
#pragma unroll
      for (int ot=0;ot<4;++ot){
#pragma unroll
        for (int kk=0;kk<2;++kk){
          const s16x8 vf = *(const s16x8*)&Vs[cur][(ot*2+b3)*528 + a7*64 + (((kk*4+quad)^a7)*8)];
          o_acc[tc][ot] = __builtin_amdgcn_mfma_f32_16x16x32_bf16(vf, pu[kk].v, o_acc[tc][ot],0,0,0);
        }
      }
    }
  }

  // epilogue: /l, write bf16 [B,S,512]  (C-layout of O^T: col=q=l16, row=dk)
#pragma unroll
  for (int tc=0;tc<2;++tc){
    const float inv = 1.0f / l_run[tc];
    const int gq = q0 + tc*16 + l16;
#pragma unroll
    for (int ot=0;ot<4;++ot){
      uint2 uu;
      uu.x = pkbf(o_acc[tc][ot][0]*inv, o_acc[tc][ot][1]*inv);
      uu.y = pkbf(o_acc[tc][ot][2]*inv, o_acc[tc][ot][3]*inv);
      *(uint2*)&Ap[((size_t)b*2048 + gq)*512 + h*64 + ot*16 + quad*4] = uu;
    }
  }
}

// =====================================================================
// residual + LayerNorm (bf16 projected output). grid 8192 x 256.
// =====================================================================
__global__ __launch_bounds__(256) void ln_kernel(
    const float* __restrict__ q, const unsigned short* __restrict__ O2,
    const float* __restrict__ gamma, const float* __restrict__ beta,
    float* __restrict__ out)
{
  const int r = blockIdx.x;
  const int t = threadIdx.x;
  const float* xq = q + (size_t)r * 512;
  const unsigned short* xo = O2 + (size_t)r * 512;
  const float x0 = xq[t]       + bf2f(xo[t]);
  const float x1 = xq[t + 256] + bf2f(xo[t + 256]);
  float s  = x0 + x1;
  float ss = x0*x0 + x1*x1;
#pragma unroll
  for (int off = 1; off < 64; off <<= 1) {
    s  += __shfl_xor(s, off);
    ss += __shfl_xor(ss, off);
  }
  __shared__ float ssum[4], ssq[4];
  const int w = t >> 6;
  if ((t & 63) == 0) { ssum[w] = s; ssq[w] = ss; }
  __syncthreads();
  const float S4 = ssum[0] + ssum[1] + ssum[2] + ssum[3];
  const float Q4 = ssq[0] + ssq[1] + ssq[2] + ssq[3];
  const float mu   = S4 * (1.0f / 512.0f);
  const float var  = Q4 * (1.0f / 512.0f) - mu * mu;
  const float rstd = rsqrtf(var + 1e-5f);
  out[(size_t)r*512 + t]       = (x0 - mu)*rstd*gamma[t] + beta[t];
  out[(size_t)r*512 + t + 256] = (x1 - mu)*rstd*gamma[t+256] + beta[t+256];
}

// =====================================================================
extern "C" void kernel_launch(void* const* d_in, const int* in_sizes, int n_in,
                              void* d_out, int out_size, void* d_ws, size_t ws_size,
                              hipStream_t stream)
{
  (void)in_sizes; (void)n_in; (void)out_size; (void)ws_size;
  const float* q    = (const float*)d_in[0];
  const float* k    = (const float*)d_in[1];
  const float* v    = (const float*)d_in[2];
  const float* mask = (const float*)d_in[3];
  const float* Wq   = (const float*)d_in[4];
  const float* bq   = (const float*)d_in[5];
  const float* Wk   = (const float*)d_in[6];
  const float* bk   = (const float*)d_in[7];
  const float* Wv   = (const float*)d_in[8];
  const float* bv   = (const float*)d_in[9];
  const float* Wo   = (const float*)d_in[10];
  const float* bo   = (const float*)d_in[11];
  const float* gamma = (const float*)d_in[12];
  const float* beta  = (const float*)d_in[13];
  float* out = (float*)d_out;

  const size_t NT = (size_t)8192*512;           // 4,194,304
  unsigned short* WtQ  = (unsigned short*)d_ws; // 4 x 512x512 bf16
  unsigned short* WtK  = WtQ + 512*512;
  unsigned short* WtV  = WtK + 512*512;
  unsigned short* WtO  = WtV + 512*512;
  unsigned short* qb   = WtO + 512*512;         // bf16 inputs [8192][512]
  unsigned short* kb   = qb + NT;
  unsigned short* vb   = kb + NT;
  unsigned short* Qp   = vb + NT;               // bf16 [B,H,S,64], pre-scaled 1/8
  unsigned short* Kp   = Qp + NT;               // bf16 [B,H,S,64]
  unsigned short* Vtg  = Kp + NT;               // bf16 [B,H,64,S]
  unsigned short* Ap   = Vtg + NT;              // bf16 [B,S,512]
  unsigned short* O2b  = Ap + NT;               // bf16 [8192][512]

  cvt_qkv<<<dim3(2048,1,3), 256, 0, stream>>>(q, k, v, qb, kb, vb);
  convert_wT<<<dim3(8,8,4), 256, 0, stream>>>(Wq, Wk, Wv, Wo, WtQ, WtK, WtV, WtO);
  gemm_m97<0><<<dim3(64,4,3), 256, 0, stream>>>(qb, kb, vb, WtQ, WtK, WtV,
                                                bq, bk, bv, Qp, Kp, Vtg, nullptr);
  attn_kernel<<<dim3(8,16,4), 256, 0, stream>>>(Qp, Kp, Vtg, mask, Ap);
  gemm_m97<1><<<dim3(64,4,1), 256, 0, stream>>>(Ap, nullptr, nullptr, WtO, nullptr, nullptr,
                                                bo, nullptr, nullptr,
                                                nullptr, nullptr, nullptr, O2b);
  ln_kernel<<<dim3(8192), 256, 0, stream>>>(q, O2b, gamma, beta, out);
}

// Round 6
// 305.086 us; speedup vs baseline: 1.1444x; 1.1444x over previous
//
#include <hip/hip_runtime.h>
#include <stdint.h>

typedef __attribute__((ext_vector_type(8))) short s16x8;   // 8 bf16 (4 VGPRs)
typedef __attribute__((ext_vector_type(4))) float f32x4;   // 4 fp32 acc

__device__ __forceinline__ unsigned short f2bf(float f){
  union { float f; unsigned u; } v; v.f = f;
  return (unsigned short)((v.u + 0x7FFFu + ((v.u>>16)&1u))>>16);
}
__device__ __forceinline__ float bf2f(unsigned short u){
  union { unsigned u; float f; } c; c.u = ((unsigned)u)<<16; return c.f;
}
#if __has_builtin(__builtin_amdgcn_cvt_pk_bf16_f32)
__device__ __forceinline__ unsigned pkbf(float a, float b){
  typedef __attribute__((ext_vector_type(2))) __bf16 bf16x2;
  union { bf16x2 v; unsigned u; } c;
  c.v = __builtin_amdgcn_cvt_pk_bf16_f32(a, b);
  return c.u;
}
#else
__device__ __forceinline__ unsigned pkbf(float a, float b){
  return (unsigned)f2bf(a) | ((unsigned)f2bf(b)<<16);
}
#endif

// async global->LDS, 16B/lane; LDS dest = wave-uniform base + lane*16.
// Global address is PER-LANE -> gather any permutation into lane-linear LDS.
__device__ __forceinline__ void g2l16(const void* g, void* l){
  auto* lp = reinterpret_cast<__attribute__((address_space(3))) unsigned int*>(
      reinterpret_cast<uintptr_t>(l));
  auto* gp = reinterpret_cast<const __attribute__((address_space(1))) unsigned int*>(
      reinterpret_cast<uintptr_t>(g));
  __builtin_amdgcn_global_load_lds(gp, lp, 16, 0, 0);
}

// =====================================================================
// Unified prep: z=0 mask fp32->bf16 (16.78M), z=1..3 q/k/v fp32->bf16,
// z=4 (first 256 blocks) weight transpose+convert. grid (8192,1,5) x 256.
// =====================================================================
__global__ __launch_bounds__(256) void prep_all(
    const float* __restrict__ mask, const float* __restrict__ q,
    const float* __restrict__ k,    const float* __restrict__ v,
    const float* __restrict__ W0, const float* __restrict__ W1,
    const float* __restrict__ W2, const float* __restrict__ W3,
    unsigned short* __restrict__ mo, unsigned short* __restrict__ qo,
    unsigned short* __restrict__ ko, unsigned short* __restrict__ vo,
    unsigned short* __restrict__ T0, unsigned short* __restrict__ T1,
    unsigned short* __restrict__ T2, unsigned short* __restrict__ T3)
{
  const int z = blockIdx.z;
  const int t = threadIdx.x;
  if (z == 4){
    if (blockIdx.x >= 256) return;
    __shared__ float Ts[64][65];
    const int wid = blockIdx.x >> 6, within = blockIdx.x & 63;
    const float* W = (wid==0)?W0:(wid==1)?W1:(wid==2)?W2:W3;
    unsigned short* Wt = (wid==0)?T0:(wid==1)?T1:(wid==2)?T2:T3;
    const int k0 = (within>>3)*64, n0 = (within&7)*64;
    {
      const int r = t>>4, c = (t&15)*4;
#pragma unroll
      for (int rr=0; rr<4; ++rr){
        const float4 w4 = *(const float4*)&W[(size_t)(k0 + r + rr*16)*512 + n0 + c];
        Ts[r+rr*16][c]   = w4.x; Ts[r+rr*16][c+1] = w4.y;
        Ts[r+rr*16][c+2] = w4.z; Ts[r+rr*16][c+3] = w4.w;
      }
    }
    __syncthreads();
    const int n = t>>2, kc = (t&3)*16;
    unsigned o[8];
#pragma unroll
    for (int i=0;i<16;i+=2) o[i>>1] = pkbf(Ts[kc+i][n], Ts[kc+i+1][n]);
    *(uint4*)&Wt[(size_t)(n0+n)*512 + k0 + kc]     = *(uint4*)&o[0];
    *(uint4*)&Wt[(size_t)(n0+n)*512 + k0 + kc + 8] = *(uint4*)&o[4];
    return;
  }
  const float* src = (z==0)?mask:(z==1)?q:(z==2)?k:v;
  unsigned short* dst = (z==0)?mo:(z==1)?qo:(z==2)?ko:vo;
  const int nblk = (z==0) ? 8192 : 2048;
  if (blockIdx.x >= nblk) return;
  const size_t i8 = ((size_t)blockIdx.x*256 + t)*8;
  const float4 a = *(const float4*)&src[i8];
  const float4 b = *(const float4*)&src[i8+4];
  uint4 o;
  o.x = pkbf(a.x,a.y); o.y = pkbf(a.z,a.w);
  o.z = pkbf(b.x,b.y); o.w = pkbf(b.z,b.w);
  *(uint4*)&dst[i8] = o;
}

// =====================================================================
// m97-style GEMM: 128x128 tile, BK=64, bf16 A/B, global_load_lds staging,
// global-side XOR chunk swizzle, LDS-transpose coalesced epilogue.
// EPI 0 (z=0,1,2): qkv -> Qp/Kp [B,H,S,64] (Q scaled 1/8), Vtg [B,H,64,S]
// EPI 1: out-proj -> bf16 [8192][512]
// =====================================================================
template<int EPI>
__global__ __launch_bounds__(256) void gemm_m97(
    const unsigned short* __restrict__ A0, const unsigned short* __restrict__ A1,
    const unsigned short* __restrict__ A2,
    const unsigned short* __restrict__ W0, const unsigned short* __restrict__ W1,
    const unsigned short* __restrict__ W2,
    const float* __restrict__ b0, const float* __restrict__ b1, const float* __restrict__ b2,
    unsigned short* __restrict__ Oq, unsigned short* __restrict__ Ok,
    unsigned short* __restrict__ Ov, unsigned short* __restrict__ Oflat)
{
  __shared__ unsigned short SM[2*128*64];   // staging As|Bs; epilogue 128x128
  unsigned short* As = SM;
  unsigned short* Bs = SM + 128*64;
  const int t = threadIdx.x;
  const int lane = t & 63;
  const int w = t >> 6;
  const int l16 = lane & 15;
  const int quad = lane >> 4;
  const int wm = w & 1, wn = w >> 1;
  const int bm = blockIdx.x, bn = blockIdx.y;
  const int z = (EPI==0) ? (int)blockIdx.z : 0;
  const unsigned short* A  = (z==0)?A0:(z==1)?A1:A2;
  const unsigned short* Wt = (z==0)?W0:(z==1)?W1:W2;
  const float* bias        = (z==0)?b0:(z==1)?b1:b2;

  const int Lr = lane >> 3;          // 0..7 row within 8-row group
  const int gc = (lane & 7) ^ Lr;    // global chunk (XOR swizzle)

  f32x4 acc[4][4];
#pragma unroll
  for(int i=0;i<4;i++)
#pragma unroll
    for(int j=0;j<4;j++) acc[i][j] = (f32x4){0.f,0.f,0.f,0.f};

  for (int kt=0; kt<8; ++kt){
    const int k0 = kt*64;
#pragma unroll
    for (int j=0;j<4;++j){
      const int rb = w*32 + j*8;
      g2l16(&A [(size_t)(bm*128 + rb + Lr)*512 + k0 + gc*8], &As[rb*64]);
      g2l16(&Wt[(size_t)(bn*128 + rb + Lr)*512 + k0 + gc*8], &Bs[rb*64]);
    }
    __syncthreads();
#pragma unroll
    for (int kk=0;kk<2;++kk){
      s16x8 af[4], bfr[4];
#pragma unroll
      for (int mt=0;mt<4;++mt){
        const int row = wm*64 + mt*16 + l16;
        af[mt] = *(const s16x8*)&As[row*64 + (((kk*4+quad) ^ (row&7))*8)];
      }
#pragma unroll
      for (int nt=0;nt<4;++nt){
        const int row = wn*64 + nt*16 + l16;
        bfr[nt] = *(const s16x8*)&Bs[row*64 + (((kk*4+quad) ^ (row&7))*8)];
      }
#pragma unroll
      for (int mt=0;mt<4;++mt)
#pragma unroll
        for (int nt=0;nt<4;++nt)
          acc[mt][nt] = __builtin_amdgcn_mfma_f32_16x16x32_bf16(af[mt], bfr[nt], acc[mt][nt], 0,0,0);
    }
    __syncthreads();
  }

  if (EPI==0 && z==2){
    // V^T epilogue: direct uint2 writes (dk-major rows, s-contiguous)
#pragma unroll
    for (int mt=0;mt<4;++mt){
      const int gm = bm*128 + wm*64 + mt*16 + quad*4;
      const int b_ = gm>>11, s = gm & 2047;
#pragma unroll
      for (int nt=0;nt<4;++nt){
        const int gn = bn*128 + wn*64 + nt*16 + l16;
        const float bv = bias[gn];
        const int hh = gn>>6, dk = gn&63;
        uint2 uu;
        uu.x = pkbf(acc[mt][nt][0]+bv, acc[mt][nt][1]+bv);
        uu.y = pkbf(acc[mt][nt][2]+bv, acc[mt][nt][3]+bv);
        *(uint2*)&Ov[(((size_t)b_*8 + hh)*64 + dk)*2048 + s] = uu;
      }
    }
    return;
  }

  // LDS-transpose epilogue: bf16(acc+bias[*scale]) -> SM[128][128] -> uint4 stores
  const float scl = (EPI==0 && z==0) ? 0.125f : 1.0f;
#pragma unroll
  for (int mt=0;mt<4;++mt){
    const int rl = wm*64 + mt*16 + quad*4;
#pragma unroll
    for (int nt=0;nt<4;++nt){
      const int cl = wn*64 + nt*16 + l16;
      const float bv = bias[bn*128 + cl];
#pragma unroll
      for (int r=0;r<4;++r)
        SM[(rl+r)*128 + cl] = f2bf((acc[mt][nt][r] + bv)*scl);
    }
  }
  __syncthreads();
#pragma unroll
  for (int i=0;i<8;++i){
    const int u = t*8 + i;            // 0..2047 uint4s
    const int row = u >> 4, seg = u & 15;
    const uint4 val = *(const uint4*)&SM[row*128 + seg*8];
    if (EPI==1){
      *(uint4*)&Oflat[(size_t)(bm*128+row)*512 + bn*128 + seg*8] = val;
    } else {
      const int col = bn*128 + seg*8;
      const int hh = col>>6, dk = col&63;
      const int gm2 = bm*128 + row;
      const int b_ = gm2>>11, s = gm2&2047;
      unsigned short* Out = (z==0)?Oq:Ok;
      *(uint4*)&Out[(((size_t)b_*8 + hh)*2048 + s)*64 + dk] = val;
    }
  }
}

// =====================================================================
// Attention v6: S^T = K Q^T; 512 thr (8 waves x 16 q = 128 q); frag-major
// K staging + group-padded V (r5-proven); bf16 mask w/ register prefetch;
// grid (g=(qt,b)=64, h=8) so same-mask blocks share an XCD's L2.
// =====================================================================
__global__ __launch_bounds__(512,4) void attn_kernel(
    const unsigned short* __restrict__ Qp, const unsigned short* __restrict__ Kp,
    const unsigned short* __restrict__ Vt, const unsigned short* __restrict__ maskb,
    unsigned short* __restrict__ Ap)
{
  // K: 8 frags x 1024B lane-linear (frag f = nt*2+kk); wave w stages frag w
  // V: 8 groups x (8 rows x 128B + 32B pad); wave w stages group w
  __shared__ unsigned short Ks[2][8*512];
  __shared__ unsigned short Vs[2][8*528];
  const int t = threadIdx.x;
  const int lane = t & 63;
  const int w = t >> 6;              // 0..7
  const int l16 = lane & 15;
  const int quad = lane >> 4;
  const int g = blockIdx.x;          // (qt,b) 0..63 — id mod 8 groups heads per XCD
  const int h = blockIdx.y;
  const int qt = g & 15, b = g >> 4;
  const int q0 = qt*128 + w*16;      // per-wave q base
  const unsigned short* Qb = Qp + ((size_t)b*8 + h)*2048*64;
  const unsigned short* Kb = Kp + ((size_t)b*8 + h)*2048*64;
  const unsigned short* Vb = Vt + ((size_t)b*8 + h)*64*2048;
  const unsigned short* mb = maskb + (size_t)b*2048*2048 + (size_t)(q0 + l16)*2048 + quad*4;

  // Q fragments (pre-scaled 1/8): B-operand of 16x16x32, n=q, k=d
  s16x8 qf[2];
#pragma unroll
  for (int kk=0;kk<2;++kk)
    qf[kk] = *(const s16x8*)&Qb[(size_t)(q0 + l16)*64 + kk*32 + quad*8];

  // staging gather offsets (elements); wave w stages K frag w / V group w
  const int koff = (((w>>1)*16 + l16)*64) + (((w&1)*4 + quad)*8);
  const int voff = ((w*8 + (lane>>3))*2048) + (((lane&7) ^ (lane>>3))*8);

  // prologue: stage tile 0 + mask tile 0
  g2l16(Kb + koff, &Ks[0][w*512]);
  g2l16(Vb + voff, &Vs[0][w*528]);
  uint2 mcur[4], mnext[4];
#pragma unroll
  for (int nt=0;nt<4;++nt) mcur[nt] = *(const uint2*)&mb[nt*16];

  f32x4 o_acc[4];
#pragma unroll
  for(int nt=0;nt<4;++nt) o_acc[nt]=(f32x4){0.f,0.f,0.f,0.f};
  float l_run = 0.f;

  const int b3 = l16>>3, a7 = l16&7;
  union U8 { unsigned u[4]; s16x8 v; };

  for (int kt=0; kt<32; ++kt){
    const int cur = kt&1;
    __syncthreads();   // buf[cur]+mcur inputs staged; prior reads of buf[cur^1] done

    // prefetch next K/V tile + next mask tile (all drain at next barrier)
    if (kt<31){
      const int kb2 = (kt+1)*64;
      g2l16(Kb + (size_t)kb2*64 + koff, &Ks[cur^1][w*512]);
      g2l16(Vb + kb2 + voff,            &Vs[cur^1][w*528]);
#pragma unroll
      for (int nt=0;nt<4;++nt) mnext[nt] = *(const uint2*)&mb[kb2 + nt*16];
    }

    // S^T = K Q^T : lane l16 = q column; rows k = nt*16+quad*4+r
    f32x4 sc[4];
#pragma unroll
    for(int nt=0;nt<4;++nt) sc[nt]=(f32x4){0.f,0.f,0.f,0.f};
#pragma unroll
    for (int nt=0;nt<4;++nt)
#pragma unroll
      for (int kk=0;kk<2;++kk){
        const s16x8 kf = *(const s16x8*)&Ks[cur][(nt*2+kk)*512 + lane*8];
        sc[nt] = __builtin_amdgcn_mfma_f32_16x16x32_bf16(kf, qf[kk], sc[nt],0,0,0);
      }

    // mask*threshold softmax (no running max: exp(-10000)=0)
    unsigned pk[8];
    float rs = 0.f;
#pragma unroll
    for (int nt=0;nt<4;++nt){
      const float m0 = bf2f((unsigned short)(mcur[nt].x & 0xffffu));
      const float m1 = bf2f((unsigned short)(mcur[nt].x >> 16));
      const float m2 = bf2f((unsigned short)(mcur[nt].y & 0xffffu));
      const float m3 = bf2f((unsigned short)(mcur[nt].y >> 16));
      float x0 = sc[nt][0]*m0, x1 = sc[nt][1]*m1, x2 = sc[nt][2]*m2, x3 = sc[nt][3]*m3;
      x0 = (x0>0.f)?x0:-10000.f; x1 = (x1>0.f)?x1:-10000.f;
      x2 = (x2>0.f)?x2:-10000.f; x3 = (x3>0.f)?x3:-10000.f;
      const float e0 = __expf(x0), e1 = __expf(x1), e2 = __expf(x2), e3 = __expf(x3);
      rs += (e0+e1)+(e2+e3);
      pk[nt*2]   = pkbf(e0, e1);
      pk[nt*2+1] = pkbf(e2, e3);
    }
    rs += __shfl_xor(rs, 16);
    rs += __shfl_xor(rs, 32);
    l_run += rs;
    // C-layout -> B-frag regroup via shuffles (r2/r3/r5-proven)
    U8 pu[2];
#pragma unroll
    for (int kk=0;kk<2;++kk)
#pragma unroll
      for (int c=0;c<4;++c){
        const int srcLane = (((quad&1)*2 + (c>>1))<<4) | l16;
        const int vA = __shfl((int)pk[kk*4 + (c&1)],     srcLane);
        const int vB = __shfl((int)pk[kk*4 + 2 + (c&1)], srcLane);
        pu[kk].u[c] = (quad < 2) ? (unsigned)vA : (unsigned)vB;
      }
    // O^T += V^T P^T  (A-operand = V^T from group-padded LDS, r5-proven)
#pragma unroll
    for (int ot=0;ot<4;++ot){
#pragma unroll
      for (int kk=0;kk<2;++kk){
        const s16x8 vf = *(const s16x8*)&Vs[cur][(ot*2+b3)*528 + a7*64 + (((kk*4+quad)^a7)*8)];
        o_acc[ot] = __builtin_amdgcn_mfma_f32_16x16x32_bf16(vf, pu[kk].v, o_acc[ot],0,0,0);
      }
    }
#pragma unroll
    for (int nt=0;nt<4;++nt) mcur[nt] = mnext[nt];
  }

  // epilogue: /l, write bf16 [B,S,512]  (C-layout of O^T: col=q=l16, row=dk)
  {
    const float inv = 1.0f / l_run;
    const int gq = q0 + l16;
#pragma unroll
    for (int ot=0;ot<4;++ot){
      uint2 uu;
      uu.x = pkbf(o_acc[ot][0]*inv, o_acc[ot][1]*inv);
      uu.y = pkbf(o_acc[ot][2]*inv, o_acc[ot][3]*inv);
      *(uint2*)&Ap[((size_t)b*2048 + gq)*512 + h*64 + ot*16 + quad*4] = uu;
    }
  }
}

// =====================================================================
// residual + LayerNorm (bf16 projected output). grid 8192 x 256.
// =====================================================================
__global__ __launch_bounds__(256) void ln_kernel(
    const float* __restrict__ q, const unsigned short* __restrict__ O2,
    const float* __restrict__ gamma, const float* __restrict__ beta,
    float* __restrict__ out)
{
  const int r = blockIdx.x;
  const int t = threadIdx.x;
  const float* xq = q + (size_t)r * 512;
  const unsigned short* xo = O2 + (size_t)r * 512;
  const float x0 = xq[t]       + bf2f(xo[t]);
  const float x1 = xq[t + 256] + bf2f(xo[t + 256]);
  float s  = x0 + x1;
  float ss = x0*x0 + x1*x1;
#pragma unroll
  for (int off = 1; off < 64; off <<= 1) {
    s  += __shfl_xor(s, off);
    ss += __shfl_xor(ss, off);
  }
  __shared__ float ssum[4], ssq[4];
  const int w = t >> 6;
  if ((t & 63) == 0) { ssum[w] = s; ssq[w] = ss; }
  __syncthreads();
  const float S4 = ssum[0] + ssum[1] + ssum[2] + ssum[3];
  const float Q4 = ssq[0] + ssq[1] + ssq[2] + ssq[3];
  const float mu   = S4 * (1.0f / 512.0f);
  const float var  = Q4 * (1.0f / 512.0f) - mu * mu;
  const float rstd = rsqrtf(var + 1e-5f);
  out[(size_t)r*512 + t]       = (x0 - mu)*rstd*gamma[t] + beta[t];
  out[(size_t)r*512 + t + 256] = (x1 - mu)*rstd*gamma[t+256] + beta[t+256];
}

// =====================================================================
extern "C" void kernel_launch(void* const* d_in, const int* in_sizes, int n_in,
                              void* d_out, int out_size, void* d_ws, size_t ws_size,
                              hipStream_t stream)
{
  (void)in_sizes; (void)n_in; (void)out_size; (void)ws_size;
  const float* q    = (const float*)d_in[0];
  const float* k    = (const float*)d_in[1];
  const float* v    = (const float*)d_in[2];
  const float* mask = (const float*)d_in[3];
  const float* Wq   = (const float*)d_in[4];
  const float* bq   = (const float*)d_in[5];
  const float* Wk   = (const float*)d_in[6];
  const float* bk   = (const float*)d_in[7];
  const float* Wv   = (const float*)d_in[8];
  const float* bv   = (const float*)d_in[9];
  const float* Wo   = (const float*)d_in[10];
  const float* bo   = (const float*)d_in[11];
  const float* gamma = (const float*)d_in[12];
  const float* beta  = (const float*)d_in[13];
  float* out = (float*)d_out;

  const size_t NT = (size_t)8192*512;           // 4,194,304
  unsigned short* WtQ  = (unsigned short*)d_ws; // 4 x 512x512 bf16
  unsigned short* WtK  = WtQ + 512*512;
  unsigned short* WtV  = WtK + 512*512;
  unsigned short* WtO  = WtV + 512*512;
  unsigned short* Mb   = WtO + 512*512;         // bf16 mask [B,S,S]
  unsigned short* qb   = Mb + (size_t)4*2048*2048;
  unsigned short* kb   = qb + NT;               // bf16 inputs [8192][512]
  unsigned short* vb   = kb + NT;
  unsigned short* Qp   = vb + NT;               // bf16 [B,H,S,64], pre-scaled 1/8
  unsigned short* Kp   = Qp + NT;               // bf16 [B,H,S,64]
  unsigned short* Vtg  = Kp + NT;               // bf16 [B,H,64,S]
  unsigned short* Ap   = Vtg + NT;              // bf16 [B,S,512]
  unsigned short* O2b  = Ap + NT;               // bf16 [8192][512]

  prep_all<<<dim3(8192,1,5), 256, 0, stream>>>(mask, q, k, v, Wq, Wk, Wv, Wo,
                                               Mb, qb, kb, vb, WtQ, WtK, WtV, WtO);
  gemm_m97<0><<<dim3(64,4,3), 256, 0, stream>>>(qb, kb, vb, WtQ, WtK, WtV,
                                                bq, bk, bv, Qp, Kp, Vtg, nullptr);
  attn_kernel<<<dim3(64,8), 512, 0, stream>>>(Qp, Kp, Vtg, Mb, Ap);
  gemm_m97<1><<<dim3(64,4,1), 256, 0, stream>>>(Ap, nullptr, nullptr, WtO, nullptr, nullptr,
                                                bo, nullptr, nullptr,
                                                nullptr, nullptr, nullptr, O2b);
  ln_kernel<<<dim3(8192), 256, 0, stream>>>(q, O2b, gamma, beta, out);
}

// Round 7
// 283.538 us; speedup vs baseline: 1.2314x; 1.0760x over previous
//
#include <hip/hip_runtime.h>
#include <stdint.h>

typedef __attribute__((ext_vector_type(8))) short s16x8;   // 8 bf16 (4 VGPRs)
typedef __attribute__((ext_vector_type(4))) float f32x4;   // 4 fp32 acc

__device__ __forceinline__ unsigned short f2bf(float f){
  union { float f; unsigned u; } v; v.f = f;
  return (unsigned short)((v.u + 0x7FFFu + ((v.u>>16)&1u))>>16);
}
__device__ __forceinline__ float bf2f(unsigned short u){
  union { unsigned u; float f; } c; c.u = ((unsigned)u)<<16; return c.f;
}
#if __has_builtin(__builtin_amdgcn_cvt_pk_bf16_f32)
__device__ __forceinline__ unsigned pkbf(float a, float b){
  typedef __attribute__((ext_vector_type(2))) __bf16 bf16x2;
  union { bf16x2 v; unsigned u; } c;
  c.v = __builtin_amdgcn_cvt_pk_bf16_f32(a, b);
  return c.u;
}
#else
__device__ __forceinline__ unsigned pkbf(float a, float b){
  return (unsigned)f2bf(a) | ((unsigned)f2bf(b)<<16);
}
#endif
#if __has_builtin(__builtin_amdgcn_exp2f)
__device__ __forceinline__ float fexp2(float x){ return __builtin_amdgcn_exp2f(x); }
#else
__device__ __forceinline__ float fexp2(float x){ return exp2f(x); }
#endif

// async global->LDS, 16B/lane; LDS dest = wave-uniform base + lane*16.
// Global address is PER-LANE -> gather any permutation into lane-linear LDS.
__device__ __forceinline__ void g2l16(const void* g, void* l){
  auto* lp = reinterpret_cast<__attribute__((address_space(3))) unsigned int*>(
      reinterpret_cast<uintptr_t>(l));
  auto* gp = reinterpret_cast<const __attribute__((address_space(1))) unsigned int*>(
      reinterpret_cast<uintptr_t>(g));
  __builtin_amdgcn_global_load_lds(gp, lp, 16, 0, 0);
}

// =====================================================================
// Unified prep: z=0 mask fp32 -> bf16 * log2e (exp2 trick), z=1..3 q/k/v
// fp32->bf16, z=4 (first 256 blocks) weight transpose. grid (8192,1,5).
// =====================================================================
__global__ __launch_bounds__(256) void prep_all(
    const float* __restrict__ mask, const float* __restrict__ q,
    const float* __restrict__ k,    const float* __restrict__ v,
    const float* __restrict__ W0, const float* __restrict__ W1,
    const float* __restrict__ W2, const float* __restrict__ W3,
    unsigned short* __restrict__ mo, unsigned short* __restrict__ qo,
    unsigned short* __restrict__ ko, unsigned short* __restrict__ vo,
    unsigned short* __restrict__ T0, unsigned short* __restrict__ T1,
    unsigned short* __restrict__ T2, unsigned short* __restrict__ T3)
{
  const int z = blockIdx.z;
  const int t = threadIdx.x;
  if (z == 4){
    if (blockIdx.x >= 256) return;
    __shared__ float Ts[64][65];
    const int wid = blockIdx.x >> 6, within = blockIdx.x & 63;
    const float* W = (wid==0)?W0:(wid==1)?W1:(wid==2)?W2:W3;
    unsigned short* Wt = (wid==0)?T0:(wid==1)?T1:(wid==2)?T2:T3;
    const int k0 = (within>>3)*64, n0 = (within&7)*64;
    {
      const int r = t>>4, c = (t&15)*4;
#pragma unroll
      for (int rr=0; rr<4; ++rr){
        const float4 w4 = *(const float4*)&W[(size_t)(k0 + r + rr*16)*512 + n0 + c];
        Ts[r+rr*16][c]   = w4.x; Ts[r+rr*16][c+1] = w4.y;
        Ts[r+rr*16][c+2] = w4.z; Ts[r+rr*16][c+3] = w4.w;
      }
    }
    __syncthreads();
    const int n = t>>2, kc = (t&3)*16;
    unsigned o[8];
#pragma unroll
    for (int i=0;i<16;i+=2) o[i>>1] = pkbf(Ts[kc+i][n], Ts[kc+i+1][n]);
    *(uint4*)&Wt[(size_t)(n0+n)*512 + k0 + kc]     = *(uint4*)&o[0];
    *(uint4*)&Wt[(size_t)(n0+n)*512 + k0 + kc + 8] = *(uint4*)&o[4];
    return;
  }
  const float* src = (z==0)?mask:(z==1)?q:(z==2)?k:v;
  unsigned short* dst = (z==0)?mo:(z==1)?qo:(z==2)?ko:vo;
  const int nblk = (z==0) ? 8192 : 2048;
  if (blockIdx.x >= nblk) return;
  const float scl = (z==0) ? 1.4426950408889634f : 1.0f;   // log2e into mask
  const size_t i8 = ((size_t)blockIdx.x*256 + t)*8;
  const float4 a = *(const float4*)&src[i8];
  const float4 b = *(const float4*)&src[i8+4];
  uint4 o;
  o.x = pkbf(a.x*scl,a.y*scl); o.y = pkbf(a.z*scl,a.w*scl);
  o.z = pkbf(b.x*scl,b.y*scl); o.w = pkbf(b.z*scl,b.w*scl);
  *(uint4*)&dst[i8] = o;
}

// =====================================================================
// GEMM 128x128, BK=64, DOUBLE-BUFFERED one-barrier (prefetch after
// barrier, drained by next barrier), global-side XOR chunk swizzle,
// LDS-transpose coalesced epilogue.
// EPI 0 (z=0,1,2): qkv -> Qp/Kp [B,H,S,64] (Q scaled 1/8), Vtg [B,H,64,S]
// EPI 1: out-proj -> bf16 [8192][512]
// =====================================================================
template<int EPI>
__global__ __launch_bounds__(256) void gemm_db(
    const unsigned short* __restrict__ A0, const unsigned short* __restrict__ A1,
    const unsigned short* __restrict__ A2,
    const unsigned short* __restrict__ W0, const unsigned short* __restrict__ W1,
    const unsigned short* __restrict__ W2,
    const float* __restrict__ b0, const float* __restrict__ b1, const float* __restrict__ b2,
    unsigned short* __restrict__ Oq, unsigned short* __restrict__ Ok,
    unsigned short* __restrict__ Ov, unsigned short* __restrict__ Oflat)
{
  __shared__ unsigned short SM[4*128*64];   // [buf][As|Bs]; epilogue reuses buf0
  const int t = threadIdx.x;
  const int lane = t & 63;
  const int w = t >> 6;
  const int l16 = lane & 15;
  const int quad = lane >> 4;
  const int wm = w & 1, wn = w >> 1;
  const int bm = blockIdx.x, bn = blockIdx.y;
  const int z = (EPI==0) ? (int)blockIdx.z : 0;
  const unsigned short* A  = (z==0)?A0:(z==1)?A1:A2;
  const unsigned short* Wt = (z==0)?W0:(z==1)?W1:W2;
  const float* bias        = (z==0)?b0:(z==1)?b1:b2;

  const int Lr = lane >> 3;          // 0..7 row within 8-row group
  const int gc = (lane & 7) ^ Lr;    // global chunk (XOR swizzle)

  f32x4 acc[4][4];
#pragma unroll
  for(int i=0;i<4;i++)
#pragma unroll
    for(int j=0;j<4;j++) acc[i][j] = (f32x4){0.f,0.f,0.f,0.f};

  // prologue: stage tile 0 into buf0
#pragma unroll
  for (int j=0;j<4;++j){
    const int rb = w*32 + j*8;
    g2l16(&A [(size_t)(bm*128 + rb + Lr)*512 + gc*8], &SM[0*8192 + rb*64]);
    g2l16(&Wt[(size_t)(bn*128 + rb + Lr)*512 + gc*8], &SM[1*8192 + rb*64]);
  }

  for (int kt=0; kt<8; ++kt){
    const int cur = kt&1;
    __syncthreads();                 // buf[cur] staged; prior reads of other buf done
    if (kt<7){
      const int k0 = (kt+1)*64;
      const int nb = (cur^1)*2;
#pragma unroll
      for (int j=0;j<4;++j){
        const int rb = w*32 + j*8;
        g2l16(&A [(size_t)(bm*128 + rb + Lr)*512 + k0 + gc*8], &SM[(size_t)nb*8192 + rb*64]);
        g2l16(&Wt[(size_t)(bn*128 + rb + Lr)*512 + k0 + gc*8], &SM[(size_t)(nb+1)*8192 + rb*64]);
      }
    }
    const unsigned short* As = &SM[(size_t)cur*2*8192];
    const unsigned short* Bs = As + 8192;
#pragma unroll
    for (int kk=0;kk<2;++kk){
      s16x8 af[4], bfr[4];
#pragma unroll
      for (int mt=0;mt<4;++mt){
        const int row = wm*64 + mt*16 + l16;
        af[mt] = *(const s16x8*)&As[row*64 + (((kk*4+quad) ^ (row&7))*8)];
      }
#pragma unroll
      for (int nt=0;nt<4;++nt){
        const int row = wn*64 + nt*16 + l16;
        bfr[nt] = *(const s16x8*)&Bs[row*64 + (((kk*4+quad) ^ (row&7))*8)];
      }
#pragma unroll
      for (int mt=0;mt<4;++mt)
#pragma unroll
        for (int nt=0;nt<4;++nt)
          acc[mt][nt] = __builtin_amdgcn_mfma_f32_16x16x32_bf16(af[mt], bfr[nt], acc[mt][nt], 0,0,0);
    }
  }

  if (EPI==0 && z==2){
    // V^T epilogue: direct uint2 writes (dk-major rows, s-contiguous)
#pragma unroll
    for (int mt=0;mt<4;++mt){
      const int gm = bm*128 + wm*64 + mt*16 + quad*4;
      const int b_ = gm>>11, s = gm & 2047;
#pragma unroll
      for (int nt=0;nt<4;++nt){
        const int gn = bn*128 + wn*64 + nt*16 + l16;
        const float bv = bias[gn];
        const int hh = gn>>6, dk = gn&63;
        uint2 uu;
        uu.x = pkbf(acc[mt][nt][0]+bv, acc[mt][nt][1]+bv);
        uu.y = pkbf(acc[mt][nt][2]+bv, acc[mt][nt][3]+bv);
        *(uint2*)&Ov[(((size_t)b_*8 + hh)*64 + dk)*2048 + s] = uu;
      }
    }
    return;
  }

  // LDS-transpose epilogue into buf0 (last compute read buf1: kt=7 -> cur=1)
  const float scl = (EPI==0 && z==0) ? 0.125f : 1.0f;
#pragma unroll
  for (int mt=0;mt<4;++mt){
    const int rl = wm*64 + mt*16 + quad*4;
#pragma unroll
    for (int nt=0;nt<4;++nt){
      const int cl = wn*64 + nt*16 + l16;
      const float bv = bias[bn*128 + cl];
#pragma unroll
      for (int r=0;r<4;++r)
        SM[(rl+r)*128 + cl] = f2bf((acc[mt][nt][r] + bv)*scl);
    }
  }
  __syncthreads();
#pragma unroll
  for (int i=0;i<8;++i){
    const int u = t*8 + i;            // 0..2047 uint4s
    const int row = u >> 4, seg = u & 15;
    const uint4 val = *(const uint4*)&SM[row*128 + seg*8];
    if (EPI==1){
      *(uint4*)&Oflat[(size_t)(bm*128+row)*512 + bn*128 + seg*8] = val;
    } else {
      const int col = bn*128 + seg*8;
      const int hh = col>>6, dk = col&63;
      const int gm2 = bm*128 + row;
      const int b_ = gm2>>11, s = gm2&2047;
      unsigned short* Out = (z==0)?Oq:Ok;
      *(uint4*)&Out[(((size_t)b_*8 + hh)*2048 + s)*64 + dk] = val;
    }
  }
}

// =====================================================================
// Attention v7: S^T = K Q^T with k-PERMUTED staging so the PV B-frag
// (k=quad*8+j) is assembled lane-locally — ZERO cross-lane regroup.
// 32 q/wave (2 tc), K/V frag reads hoisted across tc. bf16 mask
// (pre-scaled by log2e) + register prefetch; exp2 softmax; grid keeps
// r6's XCD-local mask mapping. grid (64, 8) x 256 thr (4 waves).
// =====================================================================
__global__ __launch_bounds__(256,2) void attn_kernel(
    const unsigned short* __restrict__ Qp, const unsigned short* __restrict__ Kp,
    const unsigned short* __restrict__ Vt, const unsigned short* __restrict__ maskb,
    unsigned short* __restrict__ Ap)
{
  // K: 8 frags x 1024B lane-linear; frag f=(kkb*4+pair*2+kap):
  //   lane L holds K[row = kkb*32+(L16>>2)*8+pair*4+(L16&3)][d = kap*32+(L>>4)*8 ..+8)
  // V: 8 groups x (8 rows x 128B + 32B pad) (r5/r6-proven layout)
  __shared__ unsigned short Ks[2][8*512];
  __shared__ unsigned short Vs[2][8*528];
  const int t = threadIdx.x;
  const int lane = t & 63;
  const int w = t >> 6;              // 0..3
  const int l16 = lane & 15;
  const int quad = lane >> 4;
  const int g = blockIdx.x;          // (qt,b): id mod 8 = qt mod 8 -> XCD-local mask
  const int h = blockIdx.y;
  const int qt = g & 15, b = g >> 4;
  const int q0w = qt*128 + w*32;     // per-wave q base (32 q)
  const unsigned short* Qb = Qp + ((size_t)b*8 + h)*2048*64;
  const unsigned short* Kb = Kp + ((size_t)b*8 + h)*2048*64;
  const unsigned short* Vb = Vt + ((size_t)b*8 + h)*64*2048;
  const unsigned short* mb = maskb + (size_t)b*2048*2048;

  // Q fragments (pre-scaled 1/8): B-operand, n=q, d=quad*8+j
  s16x8 qf[2][2];
#pragma unroll
  for (int tc=0;tc<2;++tc)
#pragma unroll
    for (int kap=0;kap<2;++kap)
      qf[tc][kap] = *(const s16x8*)&Qb[(size_t)(q0w + tc*16 + l16)*64 + kap*32 + quad*8];

  // staging gather offsets; wave w stages K frags {2w,2w+1}, V groups {2w,2w+1}
  int koffs[2], voffs[2];
#pragma unroll
  for (int j=0;j<2;++j){
    const int f = 2*w + j;
    const int kkb = f>>2, pair = (f>>1)&1, kap = f&1;
    const int row = kkb*32 + (l16>>2)*8 + pair*4 + (l16&3);
    koffs[j] = row*64 + kap*32 + quad*8;
    const int gg = 2*w + j;
    voffs[j] = ((gg*8 + (lane>>3))*2048) + (((lane&7) ^ (lane>>3))*8);
  }
  // prologue: stage tile 0
#pragma unroll
  for (int j=0;j<2;++j){
    g2l16(Kb + koffs[j], &Ks[0][(2*w+j)*512]);
    g2l16(Vb + voffs[j], &Vs[0][(2*w+j)*528]);
  }
  // mask rows (bf16, pre-scaled by log2e); lane's 8 k are consecutive
  const unsigned short* mrow[2] = {
    mb + (size_t)(q0w +      l16)*2048 + quad*8,
    mb + (size_t)(q0w + 16 + l16)*2048 + quad*8 };
  uint4 mcur[2][2], mnext[2][2];
#pragma unroll
  for (int tc=0;tc<2;++tc)
#pragma unroll
    for (int kkb=0;kkb<2;++kkb) mcur[tc][kkb] = *(const uint4*)&mrow[tc][kkb*32];

  f32x4 o_acc[2][4];
#pragma unroll
  for(int tc=0;tc<2;++tc)
#pragma unroll
    for(int ot=0;ot<4;++ot) o_acc[tc][ot]=(f32x4){0.f,0.f,0.f,0.f};
  float l_run[2] = {0.f, 0.f};

  const int b3 = l16>>3, a7 = l16&7;
  union U8 { unsigned u[4]; s16x8 v; };

  for (int kt=0; kt<32; ++kt){
    const int cur = kt&1;
    __syncthreads();   // buf[cur]+mcur staged; prior reads of buf[cur^1] done

    if (kt<31){
      const int kb2 = (kt+1)*64;
#pragma unroll
      for (int j=0;j<2;++j){
        g2l16(Kb + (size_t)kb2*64 + koffs[j], &Ks[cur^1][(2*w+j)*512]);
        g2l16(Vb + kb2 + voffs[j],            &Vs[cur^1][(2*w+j)*528]);
      }
#pragma unroll
      for (int tc=0;tc<2;++tc)
#pragma unroll
        for (int kkb=0;kkb<2;++kkb) mnext[tc][kkb] = *(const uint4*)&mrow[tc][kb2 + kkb*32];
    }

    // S^T = K Q^T : sc[tc][kkb][pair][r] -> k = kkb*32 + quad*8 + pair*4 + r
    f32x4 sc[2][2][2];
#pragma unroll
    for(int tc=0;tc<2;++tc)
#pragma unroll
      for(int kkb=0;kkb<2;++kkb)
#pragma unroll
        for(int pp=0;pp<2;++pp) sc[tc][kkb][pp]=(f32x4){0.f,0.f,0.f,0.f};
#pragma unroll
    for (int kkb=0;kkb<2;++kkb)
#pragma unroll
      for (int pp=0;pp<2;++pp)
#pragma unroll
        for (int kap=0;kap<2;++kap){
          const s16x8 kf = *(const s16x8*)&Ks[cur][(kkb*4+pp*2+kap)*512 + lane*8];
#pragma unroll
          for (int tc=0;tc<2;++tc)
            sc[tc][kkb][pp] = __builtin_amdgcn_mfma_f32_16x16x32_bf16(kf, qf[tc][kap], sc[tc][kkb][pp],0,0,0);
        }

    // masked-threshold softmax (exp2; mask carries log2e) + lane-local B-frag pack
    U8 pu[2][2];
#pragma unroll
    for (int tc=0;tc<2;++tc){
      float rs = 0.f;
#pragma unroll
      for (int kkb=0;kkb<2;++kkb){
        const uint4 m = mcur[tc][kkb];
        const float m0 = bf2f((unsigned short)(m.x & 0xffffu));
        const float m1 = bf2f((unsigned short)(m.x >> 16));
        const float m2 = bf2f((unsigned short)(m.y & 0xffffu));
        const float m3 = bf2f((unsigned short)(m.y >> 16));
        const float m4 = bf2f((unsigned short)(m.z & 0xffffu));
        const float m5 = bf2f((unsigned short)(m.z >> 16));
        const float m6 = bf2f((unsigned short)(m.w & 0xffffu));
        const float m7 = bf2f((unsigned short)(m.w >> 16));
        const f32x4 sa = sc[tc][kkb][0], sb = sc[tc][kkb][1];
        const float xa0 = sa[0]*m0, xa1 = sa[1]*m1, xa2 = sa[2]*m2, xa3 = sa[3]*m3;
        const float xb0 = sb[0]*m4, xb1 = sb[1]*m5, xb2 = sb[2]*m6, xb3 = sb[3]*m7;
        const float pa0 = (xa0>0.f)?fexp2(xa0):0.f, pa1 = (xa1>0.f)?fexp2(xa1):0.f;
        const float pa2 = (xa2>0.f)?fexp2(xa2):0.f, pa3 = (xa3>0.f)?fexp2(xa3):0.f;
        const float pb0 = (xb0>0.f)?fexp2(xb0):0.f, pb1 = (xb1>0.f)?fexp2(xb1):0.f;
        const float pb2 = (xb2>0.f)?fexp2(xb2):0.f, pb3 = (xb3>0.f)?fexp2(xb3):0.f;
        rs += ((pa0+pa1)+(pa2+pa3)) + ((pb0+pb1)+(pb2+pb3));
        pu[tc][kkb].u[0] = pkbf(pa0, pa1);   // k = quad*8 + 0,1
        pu[tc][kkb].u[1] = pkbf(pa2, pa3);   // k = quad*8 + 2,3
        pu[tc][kkb].u[2] = pkbf(pb0, pb1);   // k = quad*8 + 4,5
        pu[tc][kkb].u[3] = pkbf(pb2, pb3);   // k = quad*8 + 6,7
      }
      rs += __shfl_xor(rs, 16);
      rs += __shfl_xor(rs, 32);
      l_run[tc] += rs;
    }

    // O^T += V^T P^T  (A = V^T from LDS, hoisted across tc; B = pu lane-local)
#pragma unroll
    for (int ot=0;ot<4;++ot)
#pragma unroll
      for (int kkb=0;kkb<2;++kkb){
        const s16x8 vf = *(const s16x8*)&Vs[cur][(ot*2+b3)*528 + a7*64 + (((kkb*4+quad)^a7)*8)];
#pragma unroll
        for (int tc=0;tc<2;++tc)
          o_acc[tc][ot] = __builtin_amdgcn_mfma_f32_16x16x32_bf16(vf, pu[tc][kkb].v, o_acc[tc][ot],0,0,0);
      }
#pragma unroll
    for (int tc=0;tc<2;++tc)
#pragma unroll
      for (int kkb=0;kkb<2;++kkb) mcur[tc][kkb] = mnext[tc][kkb];
  }

  // epilogue: /l, write bf16 [B,S,512]  (C-layout of O^T: col=q=l16, row=dk)
#pragma unroll
  for (int tc=0;tc<2;++tc){
    const float inv = 1.0f / l_run[tc];
    const int gq = q0w + tc*16 + l16;
#pragma unroll
    for (int ot=0;ot<4;++ot){
      uint2 uu;
      uu.x = pkbf(o_acc[tc][ot][0]*inv, o_acc[tc][ot][1]*inv);
      uu.y = pkbf(o_acc[tc][ot][2]*inv, o_acc[tc][ot][3]*inv);
      *(uint2*)&Ap[((size_t)b*2048 + gq)*512 + h*64 + ot*16 + quad*4] = uu;
    }
  }
}

// =====================================================================
// residual + LayerNorm (bf16 projected output). grid 8192 x 256.
// =====================================================================
__global__ __launch_bounds__(256) void ln_kernel(
    const float* __restrict__ q, const unsigned short* __restrict__ O2,
    const float* __restrict__ gamma, const float* __restrict__ beta,
    float* __restrict__ out)
{
  const int r = blockIdx.x;
  const int t = threadIdx.x;
  const float* xq = q + (size_t)r * 512;
  const unsigned short* xo = O2 + (size_t)r * 512;
  const float x0 = xq[t]       + bf2f(xo[t]);
  const float x1 = xq[t + 256] + bf2f(xo[t + 256]);
  float s  = x0 + x1;
  float ss = x0*x0 + x1*x1;
#pragma unroll
  for (int off = 1; off < 64; off <<= 1) {
    s  += __shfl_xor(s, off);
    ss += __shfl_xor(ss, off);
  }
  __shared__ float ssum[4], ssq[4];
  const int w = t >> 6;
  if ((t & 63) == 0) { ssum[w] = s; ssq[w] = ss; }
  __syncthreads();
  const float S4 = ssum[0] + ssum[1] + ssum[2] + ssum[3];
  const float Q4 = ssq[0] + ssq[1] + ssq[2] + ssq[3];
  const float mu   = S4 * (1.0f / 512.0f);
  const float var  = Q4 * (1.0f / 512.0f) - mu * mu;
  const float rstd = rsqrtf(var + 1e-5f);
  out[(size_t)r*512 + t]       = (x0 - mu)*rstd*gamma[t] + beta[t];
  out[(size_t)r*512 + t + 256] = (x1 - mu)*rstd*gamma[t+256] + beta[t+256];
}

// =====================================================================
extern "C" void kernel_launch(void* const* d_in, const int* in_sizes, int n_in,
                              void* d_out, int out_size, void* d_ws, size_t ws_size,
                              hipStream_t stream)
{
  (void)in_sizes; (void)n_in; (void)out_size; (void)ws_size;
  const float* q    = (const float*)d_in[0];
  const float* k    = (const float*)d_in[1];
  const float* v    = (const float*)d_in[2];
  const float* mask = (const float*)d_in[3];
  const float* Wq   = (const float*)d_in[4];
  const float* bq   = (const float*)d_in[5];
  const float* Wk   = (const float*)d_in[6];
  const float* bk   = (const float*)d_in[7];
  const float* Wv   = (const float*)d_in[8];
  const float* bv   = (const float*)d_in[9];
  const float* Wo   = (const float*)d_in[10];
  const float* bo   = (const float*)d_in[11];
  const float* gamma = (const float*)d_in[12];
  const float* beta  = (const float*)d_in[13];
  float* out = (float*)d_out;

  const size_t NT = (size_t)8192*512;           // 4,194,304
  unsigned short* WtQ  = (unsigned short*)d_ws; // 4 x 512x512 bf16
  unsigned short* WtK  = WtQ + 512*512;
  unsigned short* WtV  = WtK + 512*512;
  unsigned short* WtO  = WtV + 512*512;
  unsigned short* Mb   = WtO + 512*512;         // bf16 mask*log2e [B,S,S]
  unsigned short* qb   = Mb + (size_t)4*2048*2048;
  unsigned short* kb   = qb + NT;               // bf16 inputs [8192][512]
  unsigned short* vb   = kb + NT;
  unsigned short* Qp   = vb + NT;               // bf16 [B,H,S,64], pre-scaled 1/8
  unsigned short* Kp   = Qp + NT;               // bf16 [B,H,S,64]
  unsigned short* Vtg  = Kp + NT;               // bf16 [B,H,64,S]
  unsigned short* Ap   = Vtg + NT;              // bf16 [B,S,512]
  unsigned short* O2b  = Ap + NT;               // bf16 [8192][512]

  prep_all<<<dim3(8192,1,5), 256, 0, stream>>>(mask, q, k, v, Wq, Wk, Wv, Wo,
                                               Mb, qb, kb, vb, WtQ, WtK, WtV, WtO);
  gemm_db<0><<<dim3(64,4,3), 256, 0, stream>>>(qb, kb, vb, WtQ, WtK, WtV,
                                               bq, bk, bv, Qp, Kp, Vtg, nullptr);
  attn_kernel<<<dim3(64,8), 256, 0, stream>>>(Qp, Kp, Vtg, Mb, Ap);
  gemm_db<1><<<dim3(64,4,1), 256, 0, stream>>>(Ap, nullptr, nullptr, WtO, nullptr, nullptr,
                                               bo, nullptr, nullptr,
                                               nullptr, nullptr, nullptr, O2b);
  ln_kernel<<<dim3(8192), 256, 0, stream>>>(q, O2b, gamma, beta, out);
}